// Round 3
// baseline (4515.552 us; speedup 1.0000x reference)
//
#include <hip/hip_runtime.h>
#include <hip/hip_bf16.h>

// LSTM Seq2Seq persistent kernel, fp16 MFMA + fp32 cell state. Round 3:
// Barrier poll fix. Round-2 post-mortem: relaxed agent-scope polls can hit a
// STALE local-XCD L2 line of `bar` (remote atomics update the coherent point,
// not our L2) -> progress only on random eviction (~30us/barrier, measured
// identical 30.5us/phase in r1 and r2). Fix: poll with an L1/L2-bypassing
// load (global_load_dword ... sc0 sc1) that reads the coherent point each
// iteration WITHOUT any cache invalidate. Keep exactly one acquire fence
// (buffer_inv) per barrier exit for h-state visibility. Everything else
// identical to round 2 for clean attribution.

typedef _Float16 half8 __attribute__((ext_vector_type(8)));
typedef float floatx4 __attribute__((ext_vector_type(4)));

#define NBLK 256
#define NTHR 256

__device__ __forceinline__ float sigf(float x) { return 1.f / (1.f + __expf(-x)); }
__device__ __forceinline__ float tanhf_(float x) { return 1.f - 2.f / (__expf(2.f * x) + 1.f); }

// L1+L2-bypassing read of the coherent point (no invalidate side effects).
__device__ __forceinline__ unsigned coherent_peek(const unsigned* p) {
  unsigned v;
  asm volatile("global_load_dword %0, %1, off sc0 sc1\n\t"
               "s_waitcnt vmcnt(0)"
               : "=v"(v) : "v"(p) : "memory");
  return v;
}

// Grid barrier: release-add, coherent-peek spin, one acquire fence at exit.
__device__ __forceinline__ void gbar(unsigned* bar, unsigned& tgt) {
  __syncthreads();  // drain this block's stores (vmcnt) before release
  if (threadIdx.x == 0) {
    tgt += NBLK;
    __hip_atomic_fetch_add(bar, 1u, __ATOMIC_RELEASE, __HIP_MEMORY_SCOPE_AGENT);
    while (coherent_peek(bar) < tgt)
      __builtin_amdgcn_s_sleep(1);
    __builtin_amdgcn_fence(__ATOMIC_ACQUIRE, "agent");  // one inv per phase
  }
  __syncthreads();
}

// ---------------- prep kernel: fp16 weight repack + transposes + init ----------------
__global__ void prep_kernel(
    const float* __restrict__ src,
    const float* __restrict__ eWih0, const float* __restrict__ eWhh0,
    const float* __restrict__ ebih0, const float* __restrict__ ebhh0,
    const float* __restrict__ eWih1, const float* __restrict__ eWhh1,
    const float* __restrict__ ebih1, const float* __restrict__ ebhh1,
    const float* __restrict__ dWih0, const float* __restrict__ dWhh0,
    const float* __restrict__ dbih0, const float* __restrict__ dbhh0,
    const float* __restrict__ dWih1, const float* __restrict__ dWhh1,
    const float* __restrict__ dbih1, const float* __restrict__ dbhh1,
    const float* __restrict__ fc1w, const float* __restrict__ fc1b,
    const float* __restrict__ fc4w, const float* __restrict__ fc4b,
    _Float16* W0e, _Float16* W1e, _Float16* W0d, _Float16* W1d,
    float* bs, _Float16* A1, float* c0, float* c1,
    _Float16* Xe, _Float16* Xd, _Float16* Wfc, float* bfc, unsigned* bar)
{
  const int T = gridDim.x * blockDim.x;
  const int idx = blockIdx.x * blockDim.x + threadIdx.x;

  // L0 weights: row r = [Whh0[r][0..511] | Wih0[r][0..31]], stride 544
  for (int i = idx; i < 2048 * 544; i += T) {
    int r = i / 544, k = i - r * 544;
    W0e[i] = (_Float16)(k < 512 ? eWhh0[r * 512 + k] : eWih0[r * 32 + k - 512]);
    W0d[i] = (_Float16)(k < 512 ? dWhh0[r * 512 + k] : dWih0[r * 32 + k - 512]);
  }
  // L1 weights: row r = [Whh1[r][0..511] | Wih1[r][0..511]], stride 1024
  for (int i = idx; i < 2048 * 1024; i += T) {
    int r = i >> 10, k = i & 1023;
    W1e[i] = (_Float16)(k < 512 ? eWhh1[r * 512 + k] : eWih1[r * 512 + k - 512]);
    W1d[i] = (_Float16)(k < 512 ? dWhh1[r * 512 + k] : dWih1[r * 512 + k - 512]);
  }
  // combined biases bih+bhh: [b0e | b1e | b0d | b1d]
  for (int i = idx; i < 2048; i += T) {
    bs[i]        = ebih0[i] + ebhh0[i];
    bs[2048 + i] = ebih1[i] + ebhh1[i];
    bs[4096 + i] = dbih0[i] + dbhh0[i];
    bs[6144 + i] = dbih1[i] + dbhh1[i];
  }
  // FC weights: rows 0..31 = fc4w, row 32 = fc1w, rows 33..47 zero (3 n-tiles)
  for (int i = idx; i < 48 * 512; i += T) {
    int r = i >> 9, k = i & 511;
    float v = (r < 32) ? fc4w[r * 512 + k] : (r == 32 ? fc1w[k] : 0.f);
    Wfc[i] = (_Float16)v;
  }
  for (int i = idx; i < 64; i += T)
    bfc[i] = (i < 32) ? fc4b[i] : (i == 32 ? fc1b[0] : 0.f);
  // encoder inputs step-major: Xe[t][b][f] = src[b][t][f]
  for (int i = idx; i < 96 * 512 * 32; i += T) {
    int t = i / (512 * 32); int rem = i - t * 512 * 32; int b = rem >> 5; int f = rem & 31;
    Xe[i] = (_Float16)src[(size_t)b * 96 * 32 + t * 32 + f];
  }
  // decoder x_init = src[:, 95, :]
  for (int i = idx; i < 512 * 32; i += T) {
    int b = i >> 5, f = i & 31;
    Xd[i] = (_Float16)src[(size_t)b * 96 * 32 + 95 * 32 + f];
  }
  // zero states: A1 double buffer rows [h1 | h0], plus cells
  for (int i = idx; i < 2 * 512 * 1024; i += T) A1[i] = (_Float16)0.f;
  for (int i = idx; i < 512 * 512; i += T) { c0[i] = 0.f; c1[i] = 0.f; }
  if (idx == 0) *bar = 0u;
}

// ---------------- fused GEMM + LSTM-gate phase ----------------
// MFMA 16x16x32 f16: A[m=lane&15][k=(lane>>4)*8+j], B[n=lane&15][k=...],
// D: col=lane&15, row=(lane>>4)*4+reg.  A/dst row stride 1024, X stride 32.
template <int WS, int KH, bool XP, int T>
__device__ __forceinline__ void layer_phase(
    const _Float16* __restrict__ A, const _Float16* __restrict__ X,
    const _Float16* __restrict__ W, const float* __restrict__ bsum,
    float* __restrict__ c, _Float16* __restrict__ dst,
    int m0, int row_a, int kq, int n)
{
  floatx4 acc[T][4];
#pragma unroll
  for (int t = 0; t < T; ++t)
#pragma unroll
    for (int g = 0; g < 4; ++g) {
      float b = bsum[g * 512 + n];
      acc[t][g] = (floatx4){b, b, b, b};
    }
  const _Float16* ar[T];
#pragma unroll
  for (int t = 0; t < T; ++t) ar[t] = A + (size_t)(m0 + t * 16 + row_a) * 1024 + kq * 8;
  const _Float16* wr[4];
#pragma unroll
  for (int g = 0; g < 4; ++g) wr[g] = W + (size_t)(g * 512 + n) * WS + kq * 8;

#pragma unroll 8
  for (int k0 = 0; k0 < KH; k0 += 32) {
    half8 b0 = *(const half8*)(wr[0] + k0);
    half8 b1 = *(const half8*)(wr[1] + k0);
    half8 b2 = *(const half8*)(wr[2] + k0);
    half8 b3 = *(const half8*)(wr[3] + k0);
#pragma unroll
    for (int t = 0; t < T; ++t) {
      half8 af = *(const half8*)(ar[t] + k0);
      acc[t][0] = __builtin_amdgcn_mfma_f32_16x16x32_f16(af, b0, acc[t][0], 0, 0, 0);
      acc[t][1] = __builtin_amdgcn_mfma_f32_16x16x32_f16(af, b1, acc[t][1], 0, 0, 0);
      acc[t][2] = __builtin_amdgcn_mfma_f32_16x16x32_f16(af, b2, acc[t][2], 0, 0, 0);
      acc[t][3] = __builtin_amdgcn_mfma_f32_16x16x32_f16(af, b3, acc[t][3], 0, 0, 0);
    }
  }
  if constexpr (XP) {  // x-part: one K=32 chunk, weights at row offset KH
    half8 b0 = *(const half8*)(wr[0] + KH);
    half8 b1 = *(const half8*)(wr[1] + KH);
    half8 b2 = *(const half8*)(wr[2] + KH);
    half8 b3 = *(const half8*)(wr[3] + KH);
#pragma unroll
    for (int t = 0; t < T; ++t) {
      half8 af = *(const half8*)(X + (size_t)(m0 + t * 16 + row_a) * 32 + kq * 8);
      acc[t][0] = __builtin_amdgcn_mfma_f32_16x16x32_f16(af, b0, acc[t][0], 0, 0, 0);
      acc[t][1] = __builtin_amdgcn_mfma_f32_16x16x32_f16(af, b1, acc[t][1], 0, 0, 0);
      acc[t][2] = __builtin_amdgcn_mfma_f32_16x16x32_f16(af, b2, acc[t][2], 0, 0, 0);
      acc[t][3] = __builtin_amdgcn_mfma_f32_16x16x32_f16(af, b3, acc[t][3], 0, 0, 0);
    }
  }
  // fused LSTM gate epilogue (i,f,g,o)
#pragma unroll
  for (int t = 0; t < T; ++t)
#pragma unroll
    for (int j = 0; j < 4; ++j) {
      int br = m0 + t * 16 + kq * 4 + j;
      float iv = acc[t][0][j], fv = acc[t][1][j], gv = acc[t][2][j], ov = acc[t][3][j];
      float* cp = c + (size_t)br * 512 + n;
      float cn = sigf(fv) * (*cp) + sigf(iv) * tanhf_(gv);
      float hn = sigf(ov) * tanhf_(cn);
      *cp = cn;
      dst[(size_t)br * 1024 + n] = (_Float16)hn;
    }
}

// ---------------- decoder FC heads via MFMA (redundant per block) ----------------
// Computes x(d+1)=fc4(h1) into Xd (own 16 rows per wave) and out1=fc1(h1).
__device__ __forceinline__ void fc_phase(
    const _Float16* __restrict__ h1, const _Float16* __restrict__ Wfc,
    const float* __restrict__ bfc, float* __restrict__ out,
    _Float16* __restrict__ Xd, int m0, int row_a, int kq, bool wr_out, int d)
{
  floatx4 acc[3];
#pragma unroll
  for (int nt = 0; nt < 3; ++nt) {
    float b = bfc[nt * 16 + row_a];
    acc[nt] = (floatx4){b, b, b, b};
  }
  const _Float16* arow = h1 + (size_t)(m0 + row_a) * 1024 + kq * 8;
  const _Float16* wrow[3];
#pragma unroll
  for (int nt = 0; nt < 3; ++nt) wrow[nt] = Wfc + (size_t)(nt * 16 + row_a) * 512 + kq * 8;
#pragma unroll 8
  for (int k0 = 0; k0 < 512; k0 += 32) {
    half8 af = *(const half8*)(arow + k0);
    half8 b0 = *(const half8*)(wrow[0] + k0);
    half8 b1 = *(const half8*)(wrow[1] + k0);
    half8 b2 = *(const half8*)(wrow[2] + k0);
    acc[0] = __builtin_amdgcn_mfma_f32_16x16x32_f16(af, b0, acc[0], 0, 0, 0);
    acc[1] = __builtin_amdgcn_mfma_f32_16x16x32_f16(af, b1, acc[1], 0, 0, 0);
    acc[2] = __builtin_amdgcn_mfma_f32_16x16x32_f16(af, b2, acc[2], 0, 0, 0);
  }
#pragma unroll
  for (int nt = 0; nt < 3; ++nt) {
    int col = nt * 16 + row_a;
#pragma unroll
    for (int j = 0; j < 4; ++j) {
      int row = m0 + kq * 4 + j;
      if (col < 32) Xd[row * 32 + col] = (_Float16)acc[nt][j];
      else if (col == 32 && wr_out) out[row * 24 + d] = acc[nt][j];
    }
  }
}

// ---------------- persistent recurrence kernel ----------------
__global__ void __launch_bounds__(NTHR, 1) lstm_main(
    const _Float16* __restrict__ W0e, const _Float16* __restrict__ W1e,
    const _Float16* __restrict__ W0d, const _Float16* __restrict__ W1d,
    const float* __restrict__ bs, _Float16* A1, float* c0, float* c1,
    const _Float16* __restrict__ Xe, _Float16* Xd,
    const _Float16* __restrict__ Wfc, const float* __restrict__ bfc,
    float* out, unsigned* bar)
{
  const int tid = threadIdx.x;
  const int lane = tid & 63, wv = tid >> 6;
  const int blk = (int)blockIdx.x;
  const int rowg = blk >> 5;                       // 0..7 batch group
  const int colg = (blk & 7) * 4 + ((blk >> 3) & 3);  // 0..31, XCD-local cols
  const int mbase = rowg * 64;
  const int row_a = lane & 15, kq = lane >> 4;
  const int n = colg * 16 + row_a;
  unsigned tgt = 0;

  _Float16* bufR = A1;
  _Float16* bufW = A1 + (size_t)512 * 1024;

  // ---- encoder pipeline: phase t computes L0(t) [t<=96] and L1(t-1) [t>=1].
  // t==96's "L0" is the first decoder L0 (x = x_init), L1 is enc L1(95).
  for (int t = 0; t < 97; ++t) {
    const bool dec0 = (t == 96);
    if (wv < 2) {
      layer_phase<544, 512, true, 2>(
          bufR + 512, dec0 ? Xd : Xe + (size_t)t * 512 * 32,
          dec0 ? W0d : W0e, bs + (dec0 ? 4096 : 0), c0,
          bufW + 512, mbase + wv * 32, row_a, kq, n);
    } else if (t >= 1) {
      layer_phase<1024, 1024, false, 2>(
          bufR, nullptr, W1e, bs + 2048, c1,
          bufW, mbase + (wv - 2) * 32, row_a, kq, n);
    }
    gbar(bar, tgt);
    _Float16* tmp = bufR; bufR = bufW; bufW = tmp;
  }

  // ---- decoder: 2 phases per step.
  for (int d = 0; d < 24; ++d) {
    // Phase A: h1(d) = L1d(h1(d-1), h0(d));  bufR = [h1(d-1) | h0(d)]
    layer_phase<1024, 1024, false, 1>(
        bufR, nullptr, W1d, bs + 6144, c1,
        bufW, mbase + wv * 16, row_a, kq, n);
    gbar(bar, tgt);
    // Phase B: FC heads on h1(d) (redundant per block), then L0d(d+1)
    fc_phase(bufW, Wfc, bfc, out, Xd, mbase + wv * 16, row_a, kq, colg == 0, d);
    __syncthreads();  // own-block Xd writes -> visible to own L0 loads
    if (d < 23) {
      layer_phase<544, 512, true, 1>(
          bufR + 512, Xd, W0d, bs + 4096, c0,
          bufW + 512, mbase + wv * 16, row_a, kq, n);
      gbar(bar, tgt);
    }
    _Float16* tmp = bufR; bufR = bufW; bufW = tmp;
  }
}

// ---------------- host ----------------
extern "C" void kernel_launch(void* const* d_in, const int* in_sizes, int n_in,
                              void* d_out, int out_size, void* d_ws, size_t ws_size,
                              hipStream_t stream)
{
  const int base = (in_sizes[2] == 1) ? 3 : 2;
  const float* src   = (const float*)d_in[0];
  const float* eWih0 = (const float*)d_in[base + 0];
  const float* eWhh0 = (const float*)d_in[base + 1];
  const float* ebih0 = (const float*)d_in[base + 2];
  const float* ebhh0 = (const float*)d_in[base + 3];
  const float* eWih1 = (const float*)d_in[base + 4];
  const float* eWhh1 = (const float*)d_in[base + 5];
  const float* ebih1 = (const float*)d_in[base + 6];
  const float* ebhh1 = (const float*)d_in[base + 7];
  const float* dWih0 = (const float*)d_in[base + 8];
  const float* dWhh0 = (const float*)d_in[base + 9];
  const float* dbih0 = (const float*)d_in[base + 10];
  const float* dbhh0 = (const float*)d_in[base + 11];
  const float* dWih1 = (const float*)d_in[base + 12];
  const float* dWhh1 = (const float*)d_in[base + 13];
  const float* dbih1 = (const float*)d_in[base + 14];
  const float* dbhh1 = (const float*)d_in[base + 15];
  const float* fc1w  = (const float*)d_in[base + 16];
  const float* fc1b  = (const float*)d_in[base + 17];
  const float* fc4w  = (const float*)d_in[base + 18];
  const float* fc4b  = (const float*)d_in[base + 19];

  char* p = (char*)d_ws;
  _Float16* W0e = (_Float16*)p; p += 2048 * 544 * 2;
  _Float16* W1e = (_Float16*)p; p += 2048 * 1024 * 2;
  _Float16* W0d = (_Float16*)p; p += 2048 * 544 * 2;
  _Float16* W1d = (_Float16*)p; p += 2048 * 1024 * 2;
  float*    bsv = (float*)p;    p += 8192 * 4;
  _Float16* A1  = (_Float16*)p; p += 2 * 512 * 1024 * 2;
  float*    c0  = (float*)p;    p += 512 * 512 * 4;
  float*    c1  = (float*)p;    p += 512 * 512 * 4;
  _Float16* Xe  = (_Float16*)p; p += 96 * 512 * 32 * 2;
  _Float16* Xd  = (_Float16*)p; p += 512 * 32 * 2;
  _Float16* Wfc = (_Float16*)p; p += 48 * 512 * 2;
  float*    bfc = (float*)p;    p += 64 * 4;
  unsigned* bar = (unsigned*)p; p += 256;

  hipLaunchKernelGGL(prep_kernel, dim3(1024), dim3(256), 0, stream,
      src, eWih0, eWhh0, ebih0, ebhh0, eWih1, eWhh1, ebih1, ebhh1,
      dWih0, dWhh0, dbih0, dbhh0, dWih1, dWhh1, dbih1, dbhh1,
      fc1w, fc1b, fc4w, fc4b,
      W0e, W1e, W0d, W1d, bsv, A1, c0, c1, Xe, Xd, Wfc, bfc, bar);

  float* out = (float*)d_out;
  void* kargs[] = { &W0e, &W1e, &W0d, &W1d, &bsv, &A1, &c0, &c1,
                    &Xe, &Xd, &Wfc, &bfc, &out, &bar };
  hipLaunchCooperativeKernel(reinterpret_cast<void*>(lstm_main),
                             dim3(NBLK), dim3(NTHR), kargs, 0, stream);
}

// Round 4
// 4181.107 us; speedup vs baseline: 1.0800x; 1.0800x over previous
//
#include <hip/hip_runtime.h>
#include <hip/hip_bf16.h>

// LSTM Seq2Seq persistent kernel, fp16 MFMA + fp32 cell state. Round 4:
// Barrier v3: kill the single-address atomic RMW. r1-r3 post-mortem: three
// different poll/fence strategies all measured ~30.5us/barrier -> the only
// invariant component is the 256 serialized agent-scope fetch_adds to ONE
// cacheline (~120ns each at the coherent point = 30.7us). Replace with a
// flag array: each block release-stores its phase count to flags[blk]
// (sc0 sc1, parallel, no RMW); wave 0 of each block watches all 256 flags
// with a single dwordx4 bypass load per poll round + __all ballot.
// Also: c0/c1 cell state moved to LDS (block-private slice) -> removes
// ~1.5MB/phase of dirty-L2 writeback through the per-phase wbl2 fence.

typedef _Float16 half8 __attribute__((ext_vector_type(8)));
typedef float floatx4 __attribute__((ext_vector_type(4)));
typedef unsigned uintx4 __attribute__((ext_vector_type(4)));

#define NBLK 256
#define NTHR 256

__device__ __forceinline__ float sigf(float x) { return 1.f / (1.f + __expf(-x)); }
__device__ __forceinline__ float tanhf_(float x) { return 1.f - 2.f / (__expf(2.f * x) + 1.f); }

// Grid barrier v3: per-block flag slots, no atomic RMW.
// flags[b] = number of barriers block b has completed (monotonic).
__device__ __forceinline__ void gbar(unsigned* flags, unsigned& cnt, int blk) {
  __syncthreads();            // all waves' stores issued+complete (vmcnt drain)
  cnt++;                      // every thread tracks the phase count
  if (threadIdx.x < 64) {
    if (threadIdx.x == 0) {
      // release: waitcnt + L2 writeback so our h-stores are agent-visible,
      // then bypass-store our flag straight to the coherent point.
      __builtin_amdgcn_fence(__ATOMIC_RELEASE, "agent");
      asm volatile("global_store_dword %0, %1, off sc0 sc1"
                   :: "v"(flags + blk), "v"(cnt) : "memory");
    }
    // wave 0: lane i watches flags[4i..4i+3] via one dwordx4 bypass load.
    const unsigned* p = flags + (threadIdx.x << 2);
    for (;;) {
      uintx4 f;
      asm volatile("global_load_dwordx4 %0, %1, off sc0 sc1\n\t"
                   "s_waitcnt vmcnt(0)"
                   : "=v"(f) : "v"(p) : "memory");
      bool ok = f.x >= cnt && f.y >= cnt && f.z >= cnt && f.w >= cnt;
      if (__all(ok)) break;
      __builtin_amdgcn_s_sleep(2);
    }
    if (threadIdx.x == 0)
      __builtin_amdgcn_fence(__ATOMIC_ACQUIRE, "agent");  // one inv per phase
  }
  __syncthreads();
}

// ---------------- prep kernel: fp16 weight repack + transposes + init ----------------
__global__ void prep_kernel(
    const float* __restrict__ src,
    const float* __restrict__ eWih0, const float* __restrict__ eWhh0,
    const float* __restrict__ ebih0, const float* __restrict__ ebhh0,
    const float* __restrict__ eWih1, const float* __restrict__ eWhh1,
    const float* __restrict__ ebih1, const float* __restrict__ ebhh1,
    const float* __restrict__ dWih0, const float* __restrict__ dWhh0,
    const float* __restrict__ dbih0, const float* __restrict__ dbhh0,
    const float* __restrict__ dWih1, const float* __restrict__ dWhh1,
    const float* __restrict__ dbih1, const float* __restrict__ dbhh1,
    const float* __restrict__ fc1w, const float* __restrict__ fc1b,
    const float* __restrict__ fc4w, const float* __restrict__ fc4b,
    _Float16* W0e, _Float16* W1e, _Float16* W0d, _Float16* W1d,
    float* bs, _Float16* A1,
    _Float16* Xe, _Float16* Xd, _Float16* Wfc, float* bfc, unsigned* bar)
{
  const int T = gridDim.x * blockDim.x;
  const int idx = blockIdx.x * blockDim.x + threadIdx.x;

  // L0 weights: row r = [Whh0[r][0..511] | Wih0[r][0..31]], stride 544
  for (int i = idx; i < 2048 * 544; i += T) {
    int r = i / 544, k = i - r * 544;
    W0e[i] = (_Float16)(k < 512 ? eWhh0[r * 512 + k] : eWih0[r * 32 + k - 512]);
    W0d[i] = (_Float16)(k < 512 ? dWhh0[r * 512 + k] : dWih0[r * 32 + k - 512]);
  }
  // L1 weights: row r = [Whh1[r][0..511] | Wih1[r][0..511]], stride 1024
  for (int i = idx; i < 2048 * 1024; i += T) {
    int r = i >> 10, k = i & 1023;
    W1e[i] = (_Float16)(k < 512 ? eWhh1[r * 512 + k] : eWih1[r * 512 + k - 512]);
    W1d[i] = (_Float16)(k < 512 ? dWhh1[r * 512 + k] : dWih1[r * 512 + k - 512]);
  }
  // combined biases bih+bhh: [b0e | b1e | b0d | b1d]
  for (int i = idx; i < 2048; i += T) {
    bs[i]        = ebih0[i] + ebhh0[i];
    bs[2048 + i] = ebih1[i] + ebhh1[i];
    bs[4096 + i] = dbih0[i] + dbhh0[i];
    bs[6144 + i] = dbih1[i] + dbhh1[i];
  }
  // FC weights: rows 0..31 = fc4w, row 32 = fc1w, rows 33..47 zero (3 n-tiles)
  for (int i = idx; i < 48 * 512; i += T) {
    int r = i >> 9, k = i & 511;
    float v = (r < 32) ? fc4w[r * 512 + k] : (r == 32 ? fc1w[k] : 0.f);
    Wfc[i] = (_Float16)v;
  }
  for (int i = idx; i < 64; i += T)
    bfc[i] = (i < 32) ? fc4b[i] : (i == 32 ? fc1b[0] : 0.f);
  // encoder inputs step-major: Xe[t][b][f] = src[b][t][f]
  for (int i = idx; i < 96 * 512 * 32; i += T) {
    int t = i / (512 * 32); int rem = i - t * 512 * 32; int b = rem >> 5; int f = rem & 31;
    Xe[i] = (_Float16)src[(size_t)b * 96 * 32 + t * 32 + f];
  }
  // decoder x_init = src[:, 95, :]
  for (int i = idx; i < 512 * 32; i += T) {
    int b = i >> 5, f = i & 31;
    Xd[i] = (_Float16)src[(size_t)b * 96 * 32 + 95 * 32 + f];
  }
  // zero states: A1 double buffer rows [h1 | h0]
  for (int i = idx; i < 2 * 512 * 1024; i += T) A1[i] = (_Float16)0.f;
  // zero barrier flags (workspace is poisoned 0xAA before every launch!)
  for (int i = idx; i < 256; i += T) bar[i] = 0u;
}

// ---------------- fused GEMM + LSTM-gate phase ----------------
// MFMA 16x16x32 f16: A[m=lane&15][k=(lane>>4)*8+j], B[n=lane&15][k=...],
// D: col=lane&15, row=(lane>>4)*4+reg.  A/dst row stride 1024, X stride 32.
// c is an LDS slice [64 rows x 17 (padded)] private to the block.
template <int WS, int KH, bool XP, int T>
__device__ __forceinline__ void layer_phase(
    const _Float16* __restrict__ A, const _Float16* __restrict__ X,
    const _Float16* __restrict__ W, const float* __restrict__ bsum,
    float* c, _Float16* __restrict__ dst,
    int m0, int row_a, int kq, int n)
{
  floatx4 acc[T][4];
#pragma unroll
  for (int t = 0; t < T; ++t)
#pragma unroll
    for (int g = 0; g < 4; ++g) {
      float b = bsum[g * 512 + n];
      acc[t][g] = (floatx4){b, b, b, b};
    }
  const _Float16* ar[T];
#pragma unroll
  for (int t = 0; t < T; ++t) ar[t] = A + (size_t)(m0 + t * 16 + row_a) * 1024 + kq * 8;
  const _Float16* wr[4];
#pragma unroll
  for (int g = 0; g < 4; ++g) wr[g] = W + (size_t)(g * 512 + n) * WS + kq * 8;

#pragma unroll 8
  for (int k0 = 0; k0 < KH; k0 += 32) {
    half8 b0 = *(const half8*)(wr[0] + k0);
    half8 b1 = *(const half8*)(wr[1] + k0);
    half8 b2 = *(const half8*)(wr[2] + k0);
    half8 b3 = *(const half8*)(wr[3] + k0);
#pragma unroll
    for (int t = 0; t < T; ++t) {
      half8 af = *(const half8*)(ar[t] + k0);
      acc[t][0] = __builtin_amdgcn_mfma_f32_16x16x32_f16(af, b0, acc[t][0], 0, 0, 0);
      acc[t][1] = __builtin_amdgcn_mfma_f32_16x16x32_f16(af, b1, acc[t][1], 0, 0, 0);
      acc[t][2] = __builtin_amdgcn_mfma_f32_16x16x32_f16(af, b2, acc[t][2], 0, 0, 0);
      acc[t][3] = __builtin_amdgcn_mfma_f32_16x16x32_f16(af, b3, acc[t][3], 0, 0, 0);
    }
  }
  if constexpr (XP) {  // x-part: one K=32 chunk, weights at row offset KH
    half8 b0 = *(const half8*)(wr[0] + KH);
    half8 b1 = *(const half8*)(wr[1] + KH);
    half8 b2 = *(const half8*)(wr[2] + KH);
    half8 b3 = *(const half8*)(wr[3] + KH);
#pragma unroll
    for (int t = 0; t < T; ++t) {
      half8 af = *(const half8*)(X + (size_t)(m0 + t * 16 + row_a) * 32 + kq * 8);
      acc[t][0] = __builtin_amdgcn_mfma_f32_16x16x32_f16(af, b0, acc[t][0], 0, 0, 0);
      acc[t][1] = __builtin_amdgcn_mfma_f32_16x16x32_f16(af, b1, acc[t][1], 0, 0, 0);
      acc[t][2] = __builtin_amdgcn_mfma_f32_16x16x32_f16(af, b2, acc[t][2], 0, 0, 0);
      acc[t][3] = __builtin_amdgcn_mfma_f32_16x16x32_f16(af, b3, acc[t][3], 0, 0, 0);
    }
  }
  // fused LSTM gate epilogue (i,f,g,o); c slice indexed (br&63, row_a)
#pragma unroll
  for (int t = 0; t < T; ++t)
#pragma unroll
    for (int j = 0; j < 4; ++j) {
      int br = m0 + t * 16 + kq * 4 + j;
      float iv = acc[t][0][j], fv = acc[t][1][j], gv = acc[t][2][j], ov = acc[t][3][j];
      float* cp = c + ((br & 63) * 17 + row_a);
      float cn = sigf(fv) * (*cp) + sigf(iv) * tanhf_(gv);
      float hn = sigf(ov) * tanhf_(cn);
      *cp = cn;
      dst[(size_t)br * 1024 + n] = (_Float16)hn;
    }
}

// ---------------- decoder FC heads via MFMA (redundant per block) ----------------
// Computes x(d+1)=fc4(h1) into Xd (own 16 rows per wave) and out1=fc1(h1).
__device__ __forceinline__ void fc_phase(
    const _Float16* __restrict__ h1, const _Float16* __restrict__ Wfc,
    const float* __restrict__ bfc, float* __restrict__ out,
    _Float16* __restrict__ Xd, int m0, int row_a, int kq, bool wr_out, int d)
{
  floatx4 acc[3];
#pragma unroll
  for (int nt = 0; nt < 3; ++nt) {
    float b = bfc[nt * 16 + row_a];
    acc[nt] = (floatx4){b, b, b, b};
  }
  const _Float16* arow = h1 + (size_t)(m0 + row_a) * 1024 + kq * 8;
  const _Float16* wrow[3];
#pragma unroll
  for (int nt = 0; nt < 3; ++nt) wrow[nt] = Wfc + (size_t)(nt * 16 + row_a) * 512 + kq * 8;
#pragma unroll 8
  for (int k0 = 0; k0 < 512; k0 += 32) {
    half8 af = *(const half8*)(arow + k0);
    half8 b0 = *(const half8*)(wrow[0] + k0);
    half8 b1 = *(const half8*)(wrow[1] + k0);
    half8 b2 = *(const half8*)(wrow[2] + k0);
    acc[0] = __builtin_amdgcn_mfma_f32_16x16x32_f16(af, b0, acc[0], 0, 0, 0);
    acc[1] = __builtin_amdgcn_mfma_f32_16x16x32_f16(af, b1, acc[1], 0, 0, 0);
    acc[2] = __builtin_amdgcn_mfma_f32_16x16x32_f16(af, b2, acc[2], 0, 0, 0);
  }
#pragma unroll
  for (int nt = 0; nt < 3; ++nt) {
    int col = nt * 16 + row_a;
#pragma unroll
    for (int j = 0; j < 4; ++j) {
      int row = m0 + kq * 4 + j;
      if (col < 32) Xd[row * 32 + col] = (_Float16)acc[nt][j];
      else if (col == 32 && wr_out) out[row * 24 + d] = acc[nt][j];
    }
  }
}

// ---------------- persistent recurrence kernel ----------------
__global__ void __launch_bounds__(NTHR, 1) lstm_main(
    const _Float16* __restrict__ W0e, const _Float16* __restrict__ W1e,
    const _Float16* __restrict__ W0d, const _Float16* __restrict__ W1d,
    const float* __restrict__ bs, _Float16* A1,
    const _Float16* __restrict__ Xe, _Float16* Xd,
    const _Float16* __restrict__ Wfc, const float* __restrict__ bfc,
    float* out, unsigned* bar)
{
  const int tid = threadIdx.x;
  const int lane = tid & 63, wv = tid >> 6;
  const int blk = (int)blockIdx.x;
  const int rowg = blk >> 5;                       // 0..7 batch group
  const int colg = (blk & 7) * 4 + ((blk >> 3) & 3);  // 0..31, XCD-local cols
  const int mbase = rowg * 64;
  const int row_a = lane & 15, kq = lane >> 4;
  const int n = colg * 16 + row_a;
  unsigned cnt = 0;

  // block-private cell state in LDS: [64 batch rows x 16 cols], padded to 17
  __shared__ float c0s[64 * 17];
  __shared__ float c1s[64 * 17];
  for (int i = tid; i < 64 * 17; i += NTHR) { c0s[i] = 0.f; c1s[i] = 0.f; }
  __syncthreads();

  _Float16* bufR = A1;
  _Float16* bufW = A1 + (size_t)512 * 1024;

  // ---- encoder pipeline: phase t computes L0(t) [t<=96] and L1(t-1) [t>=1].
  // t==96's "L0" is the first decoder L0 (x = x_init), L1 is enc L1(95).
  for (int t = 0; t < 97; ++t) {
    const bool dec0 = (t == 96);
    if (wv < 2) {
      layer_phase<544, 512, true, 2>(
          bufR + 512, dec0 ? Xd : Xe + (size_t)t * 512 * 32,
          dec0 ? W0d : W0e, bs + (dec0 ? 4096 : 0), c0s,
          bufW + 512, mbase + wv * 32, row_a, kq, n);
    } else if (t >= 1) {
      layer_phase<1024, 1024, false, 2>(
          bufR, nullptr, W1e, bs + 2048, c1s,
          bufW, mbase + (wv - 2) * 32, row_a, kq, n);
    }
    gbar(bar, cnt, blk);
    _Float16* tmp = bufR; bufR = bufW; bufW = tmp;
  }

  // ---- decoder: 2 phases per step.
  for (int d = 0; d < 24; ++d) {
    // Phase A: h1(d) = L1d(h1(d-1), h0(d));  bufR = [h1(d-1) | h0(d)]
    layer_phase<1024, 1024, false, 1>(
        bufR, nullptr, W1d, bs + 6144, c1s,
        bufW, mbase + wv * 16, row_a, kq, n);
    gbar(bar, cnt, blk);
    // Phase B: FC heads on h1(d) (redundant per block), then L0d(d+1)
    fc_phase(bufW, Wfc, bfc, out, Xd, mbase + wv * 16, row_a, kq, colg == 0, d);
    __syncthreads();  // own-block Xd writes -> visible to own L0 loads
    if (d < 23) {
      layer_phase<544, 512, true, 1>(
          bufR + 512, Xd, W0d, bs + 4096, c0s,
          bufW + 512, mbase + wv * 16, row_a, kq, n);
      gbar(bar, cnt, blk);
    }
    _Float16* tmp = bufR; bufR = bufW; bufW = tmp;
  }
}

// ---------------- host ----------------
extern "C" void kernel_launch(void* const* d_in, const int* in_sizes, int n_in,
                              void* d_out, int out_size, void* d_ws, size_t ws_size,
                              hipStream_t stream)
{
  const int base = (in_sizes[2] == 1) ? 3 : 2;
  const float* src   = (const float*)d_in[0];
  const float* eWih0 = (const float*)d_in[base + 0];
  const float* eWhh0 = (const float*)d_in[base + 1];
  const float* ebih0 = (const float*)d_in[base + 2];
  const float* ebhh0 = (const float*)d_in[base + 3];
  const float* eWih1 = (const float*)d_in[base + 4];
  const float* eWhh1 = (const float*)d_in[base + 5];
  const float* ebih1 = (const float*)d_in[base + 6];
  const float* ebhh1 = (const float*)d_in[base + 7];
  const float* dWih0 = (const float*)d_in[base + 8];
  const float* dWhh0 = (const float*)d_in[base + 9];
  const float* dbih0 = (const float*)d_in[base + 10];
  const float* dbhh0 = (const float*)d_in[base + 11];
  const float* dWih1 = (const float*)d_in[base + 12];
  const float* dWhh1 = (const float*)d_in[base + 13];
  const float* dbih1 = (const float*)d_in[base + 14];
  const float* dbhh1 = (const float*)d_in[base + 15];
  const float* fc1w  = (const float*)d_in[base + 16];
  const float* fc1b  = (const float*)d_in[base + 17];
  const float* fc4w  = (const float*)d_in[base + 18];
  const float* fc4b  = (const float*)d_in[base + 19];

  char* p = (char*)d_ws;
  _Float16* W0e = (_Float16*)p; p += 2048 * 544 * 2;
  _Float16* W1e = (_Float16*)p; p += 2048 * 1024 * 2;
  _Float16* W0d = (_Float16*)p; p += 2048 * 544 * 2;
  _Float16* W1d = (_Float16*)p; p += 2048 * 1024 * 2;
  float*    bsv = (float*)p;    p += 8192 * 4;
  _Float16* A1  = (_Float16*)p; p += 2 * 512 * 1024 * 2;
  _Float16* Xe  = (_Float16*)p; p += 96 * 512 * 32 * 2;
  _Float16* Xd  = (_Float16*)p; p += 512 * 32 * 2;
  _Float16* Wfc = (_Float16*)p; p += 48 * 512 * 2;
  float*    bfc = (float*)p;    p += 64 * 4;
  unsigned* bar = (unsigned*)p; p += 1024;   // 256 x 4B flag slots

  hipLaunchKernelGGL(prep_kernel, dim3(1024), dim3(256), 0, stream,
      src, eWih0, eWhh0, ebih0, ebhh0, eWih1, eWhh1, ebih1, ebhh1,
      dWih0, dWhh0, dbih0, dbhh0, dWih1, dWhh1, dbih1, dbhh1,
      fc1w, fc1b, fc4w, fc4b,
      W0e, W1e, W0d, W1d, bsv, A1, Xe, Xd, Wfc, bfc, bar);

  float* out = (float*)d_out;
  void* kargs[] = { &W0e, &W1e, &W0d, &W1d, &bsv, &A1,
                    &Xe, &Xd, &Wfc, &bfc, &out, &bar };
  hipLaunchCooperativeKernel(reinterpret_cast<void*>(lstm_main),
                             dim3(NBLK), dim3(NTHR), kargs, 0, stream);
}

// Round 7
// 2668.433 us; speedup vs baseline: 1.6922x; 1.5669x over previous
//
#include <hip/hip_runtime.h>
#include <hip/hip_bf16.h>

// LSTM Seq2Seq persistent kernel, fp16 MFMA + fp32 cell state. Round 7:
// r6 structure (fence-free phases, coherent-point h exchange, 32x32 tiles,
// wave=gate, LDS A-staging, register cell state) with two fixes:
// 1) B-fragment pointers were missing the per-lane K offset (+kq*8) that
//    r2-r5 had -> every MFMA B operand was wrong (absmax 3.9e-2). Restored
//    on w0r*/w1r*/fc wr.
// 2) epi's bypass h-stores are inline asm -> invisible to the compiler's
//    waitcnt pass -> the s_barrier inside gbar may not drain them before
//    the flag store. Each wave now drains its own vmcnt on gbar entry.

typedef _Float16 half8 __attribute__((ext_vector_type(8)));
typedef _Float16 half4 __attribute__((ext_vector_type(4)));
typedef float floatx4 __attribute__((ext_vector_type(4)));
typedef unsigned uintx4 __attribute__((ext_vector_type(4)));

#define NBLK 256
#define NTHR 256

__device__ __forceinline__ float sigf(float x) { return 1.f / (1.f + __expf(-x)); }
__device__ __forceinline__ float tanhf_(float x) { return 1.f - 2.f / (__expf(2.f * x) + 1.f); }

// Grid barrier: flag store + coherent-point polls. NO fences, no RMW.
// All cross-block data moves via sc0 sc1 ops, so no cache maintenance is
// needed; we only need ordering: drain own wave's (asm, untracked) stores,
// then __syncthreads, then publish the flag.
__device__ __forceinline__ void gbar(unsigned* gf, unsigned& cnt, int blk) {
  asm volatile("s_waitcnt vmcnt(0)" ::: "memory");  // drain own bypass stores
  __syncthreads();                                  // all waves drained
  cnt++;
  if (threadIdx.x == 0)
    asm volatile("global_store_dword %0, %1, off sc0 sc1"
                 :: "v"(gf + blk), "v"(cnt) : "memory");
  if (threadIdx.x < 64) {
    const unsigned* p = gf + (threadIdx.x << 2);
    for (;;) {
      uintx4 f;
      asm volatile("global_load_dwordx4 %0, %1, off sc0 sc1\n\t"
                   "s_waitcnt vmcnt(0)" : "=v"(f) : "v"(p) : "memory");
      if (__all(f.x >= cnt && f.y >= cnt && f.z >= cnt && f.w >= cnt)) break;
      __builtin_amdgcn_s_sleep(1);
    }
  }
  __syncthreads();
}

// ---------------- prep kernel ----------------
__global__ void prep_kernel(
    const float* __restrict__ src,
    const float* __restrict__ eWih0, const float* __restrict__ eWhh0,
    const float* __restrict__ ebih0, const float* __restrict__ ebhh0,
    const float* __restrict__ eWih1, const float* __restrict__ eWhh1,
    const float* __restrict__ ebih1, const float* __restrict__ ebhh1,
    const float* __restrict__ dWih0, const float* __restrict__ dWhh0,
    const float* __restrict__ dbih0, const float* __restrict__ dbhh0,
    const float* __restrict__ dWih1, const float* __restrict__ dWhh1,
    const float* __restrict__ dbih1, const float* __restrict__ dbhh1,
    const float* __restrict__ fc1w, const float* __restrict__ fc1b,
    const float* __restrict__ fc4w, const float* __restrict__ fc4b,
    _Float16* W0e, _Float16* W1e, _Float16* W0d, _Float16* W1d,
    float* bs, _Float16* A1,
    _Float16* Xe, _Float16* Xd, _Float16* Wfc, float* bfc, unsigned* gflags)
{
  const int T = gridDim.x * blockDim.x;
  const int idx = blockIdx.x * blockDim.x + threadIdx.x;

  // L0 weights: row r = [Whh0[r][0..511] | Wih0[r][0..31]], stride 544
  for (int i = idx; i < 2048 * 544; i += T) {
    int r = i / 544, k = i - r * 544;
    W0e[i] = (_Float16)(k < 512 ? eWhh0[r * 512 + k] : eWih0[r * 32 + k - 512]);
    W0d[i] = (_Float16)(k < 512 ? dWhh0[r * 512 + k] : dWih0[r * 32 + k - 512]);
  }
  // L1 weights: row r = [Whh1 (k:0..511 <-> h1) | Wih1 (k:512..1023 <-> h0)]
  for (int i = idx; i < 2048 * 1024; i += T) {
    int r = i >> 10, k = i & 1023;
    W1e[i] = (_Float16)(k < 512 ? eWhh1[r * 512 + k] : eWih1[r * 512 + k - 512]);
    W1d[i] = (_Float16)(k < 512 ? dWhh1[r * 512 + k] : dWih1[r * 512 + k - 512]);
  }
  // combined biases bih+bhh: [b0e | b1e | b0d | b1d]
  for (int i = idx; i < 2048; i += T) {
    bs[i]        = ebih0[i] + ebhh0[i];
    bs[2048 + i] = ebih1[i] + ebhh1[i];
    bs[4096 + i] = dbih0[i] + dbhh0[i];
    bs[6144 + i] = dbih1[i] + dbhh1[i];
  }
  // FC weights: rows 0..31 = fc4w, row 32 = fc1w, rows 33..47 zero
  for (int i = idx; i < 48 * 512; i += T) {
    int r = i >> 9, k = i & 511;
    float v = (r < 32) ? fc4w[r * 512 + k] : (r == 32 ? fc1w[k] : 0.f);
    Wfc[i] = (_Float16)v;
  }
  for (int i = idx; i < 64; i += T)
    bfc[i] = (i < 32) ? fc4b[i] : (i == 32 ? fc1b[0] : 0.f);
  // encoder inputs step-major: Xe[t][b][f] = src[b][t][f]
  for (int i = idx; i < 96 * 512 * 32; i += T) {
    int t = i / (512 * 32); int rem = i - t * 512 * 32; int b = rem >> 5; int f = rem & 31;
    Xe[i] = (_Float16)src[(size_t)b * 96 * 32 + t * 32 + f];
  }
  // decoder x_init = src[:, 95, :]
  for (int i = idx; i < 512 * 32; i += T) {
    int b = i >> 5, f = i & 31;
    Xd[i] = (_Float16)src[(size_t)b * 96 * 32 + 95 * 32 + f];
  }
  // zero h double-buffer [h1 | h0] and barrier flags (ws is 0xAA-poisoned)
  for (int i = idx; i < 2 * 512 * 1024; i += T) A1[i] = (_Float16)0.f;
  for (int i = idx; i < 256; i += T) gflags[i] = 0u;
}

// ---------------- A staging: bypass loads -> LDS frag-order ----------------
// 16 chunks (512 cols) of the block's 32 rows from src cols [colbase..+511].
// LDS layout: slot c in [0,16): [c][mt][lane][8 halves], lane = kq*16+m.
__device__ __forceinline__ void stage16(const _Float16* src, int colbase,
                                        _Float16* Ast, int row0, int tid)
{
#pragma unroll
  for (int i0 = 0; i0 < 8; i0 += 4) {
    const _Float16* p[4]; int off[4];
#pragma unroll
    for (int i = 0; i < 4; ++i) {
      int g = tid + (i0 + i) * NTHR;      // 0..2047
      int c = g >> 7, r7 = g & 127, mt = r7 >> 6, l = r7 & 63;
      int row = mt * 16 + (l & 15);
      p[i] = src + (size_t)(row0 + row) * 1024 + colbase + c * 32 + (l >> 4) * 8;
      off[i] = ((c * 2 + mt) * 64 + l) * 8;
    }
    half8 v0, v1, v2, v3;
    asm volatile(
      "global_load_dwordx4 %0, %4, off sc0 sc1\n\t"
      "global_load_dwordx4 %1, %5, off sc0 sc1\n\t"
      "global_load_dwordx4 %2, %6, off sc0 sc1\n\t"
      "global_load_dwordx4 %3, %7, off sc0 sc1\n\t"
      "s_waitcnt vmcnt(0)"
      : "=v"(v0), "=v"(v1), "=v"(v2), "=v"(v3)
      : "v"(p[0]), "v"(p[1]), "v"(p[2]), "v"(p[3]) : "memory");
    *(half8*)(Ast + off[0]) = v0; *(half8*)(Ast + off[1]) = v1;
    *(half8*)(Ast + off[2]) = v2; *(half8*)(Ast + off[3]) = v3;
  }
}

// ---------------- GEMM pieces (wave = one gate, 2 mt x 2 nt tiles) ----------
__device__ __forceinline__ void acc_init(floatx4 (&acc)[2][2],
    const float* __restrict__ bsum, int g, int col0, int row_a)
{
#pragma unroll
  for (int nt = 0; nt < 2; ++nt) {
    float b = bsum[g * 512 + col0 + nt * 16 + row_a];
    acc[0][nt] = (floatx4){b, b, b, b};
    acc[1][nt] = (floatx4){b, b, b, b};
  }
}

// wr0/wr1 must already include the per-lane kq*8 K offset.
template <int NCH>
__device__ __forceinline__ void gemm_part(floatx4 (&acc)[2][2],
    const _Float16* Ast, const _Float16* __restrict__ wr0,
    const _Float16* __restrict__ wr1, int koff, int lane)
{
#pragma unroll 8
  for (int c = 0; c < NCH; ++c) {
    half8 a0 = *(const half8*)(Ast + ((c * 2 + 0) * 64 + lane) * 8);
    half8 a1 = *(const half8*)(Ast + ((c * 2 + 1) * 64 + lane) * 8);
    half8 b0 = *(const half8*)(wr0 + koff + c * 32);
    half8 b1 = *(const half8*)(wr1 + koff + c * 32);
    acc[0][0] = __builtin_amdgcn_mfma_f32_16x16x32_f16(a0, b0, acc[0][0], 0, 0, 0);
    acc[1][0] = __builtin_amdgcn_mfma_f32_16x16x32_f16(a1, b0, acc[1][0], 0, 0, 0);
    acc[0][1] = __builtin_amdgcn_mfma_f32_16x16x32_f16(a0, b1, acc[0][1], 0, 0, 0);
    acc[1][1] = __builtin_amdgcn_mfma_f32_16x16x32_f16(a1, b1, acc[1][1], 0, 0, 0);
  }
}

__device__ __forceinline__ void gemm_x(floatx4 (&acc)[2][2],
    const _Float16* __restrict__ X, const _Float16* __restrict__ wr0,
    const _Float16* __restrict__ wr1, int koff, int row0, int lane)
{
  const int row_a = lane & 15, kq = lane >> 4;
  half8 a0 = *(const half8*)(X + (size_t)(row0 + row_a) * 32 + kq * 8);
  half8 a1 = *(const half8*)(X + (size_t)(row0 + 16 + row_a) * 32 + kq * 8);
  half8 b0 = *(const half8*)(wr0 + koff);
  half8 b1 = *(const half8*)(wr1 + koff);
  acc[0][0] = __builtin_amdgcn_mfma_f32_16x16x32_f16(a0, b0, acc[0][0], 0, 0, 0);
  acc[1][0] = __builtin_amdgcn_mfma_f32_16x16x32_f16(a1, b0, acc[1][0], 0, 0, 0);
  acc[0][1] = __builtin_amdgcn_mfma_f32_16x16x32_f16(a0, b1, acc[0][1], 0, 0, 0);
  acc[1][1] = __builtin_amdgcn_mfma_f32_16x16x32_f16(a1, b1, acc[1][1], 0, 0, 0);
}

__device__ __forceinline__ void zwrite(const floatx4 (&acc)[2][2],
    float* Zacc, int g, int lane)
{
  const int row_a = lane & 15, kq = lane >> 4;
#pragma unroll
  for (int mt = 0; mt < 2; ++mt)
#pragma unroll
    for (int nt = 0; nt < 2; ++nt)
#pragma unroll
      for (int j = 0; j < 4; ++j)
        Zacc[g * 1152 + (mt * 16 + kq * 4 + j) * 36 + nt * 16 + row_a] = acc[mt][nt][j];
}

// LSTM pointwise epilogue; thread owns rows/cols (r=tid>>3, 4 cols at
// (tid&7)*4) with cell state in its registers. Direct dwordx2 bypass store.
__device__ __forceinline__ void epi(const float* Zacc, float (&cr)[4],
    _Float16* bufW, int row0, int dcol0, int tid)
{
  int r = tid >> 3, cb = (tid & 7) * 4;
  half4 hv;
#pragma unroll
  for (int k = 0; k < 4; ++k) {
    float iv = Zacc[0 * 1152 + r * 36 + cb + k];
    float fv = Zacc[1 * 1152 + r * 36 + cb + k];
    float gv = Zacc[2 * 1152 + r * 36 + cb + k];
    float ov = Zacc[3 * 1152 + r * 36 + cb + k];
    float cn = sigf(fv) * cr[k] + sigf(iv) * tanhf_(gv);
    cr[k] = cn;
    hv[k] = (_Float16)(sigf(ov) * tanhf_(cn));
  }
  unsigned long long hvu;
  __builtin_memcpy(&hvu, &hv, 8);
  const _Float16* dp = bufW + (size_t)(row0 + r) * 1024 + dcol0 + cb;
  asm volatile("global_store_dwordx2 %0, %1, off sc0 sc1"
               :: "v"(dp), "v"(hvu) : "memory");
}

// ---------------- decoder FC heads (per block, own 32 rows) ----------------
__device__ __forceinline__ void fc_do(const _Float16* Ast,
    const _Float16* __restrict__ Wfc, const float* __restrict__ bfc,
    float* __restrict__ out, _Float16* __restrict__ Xd,
    int row0, int wv, int lane, bool wr_out, int d)
{
  const int row_a = lane & 15, kq = lane >> 4;
#pragma unroll
  for (int rep = 0; rep < 2; ++rep) {
    int ft = wv + rep * 4;
    if (ft < 6) {
      int mt = ft / 3, nt = ft % 3;
      float b = bfc[nt * 16 + row_a];
      floatx4 acc = (floatx4){b, b, b, b};
      const _Float16* wr = Wfc + (size_t)(nt * 16 + row_a) * 512 + kq * 8;
#pragma unroll 8
      for (int c = 0; c < 16; ++c) {
        half8 a = *(const half8*)(Ast + ((c * 2 + mt) * 64 + lane) * 8);
        half8 bb = *(const half8*)(wr + c * 32);
        acc = __builtin_amdgcn_mfma_f32_16x16x32_f16(a, bb, acc, 0, 0, 0);
      }
      int col = nt * 16 + row_a;
#pragma unroll
      for (int j = 0; j < 4; ++j) {
        int row = row0 + mt * 16 + kq * 4 + j;
        if (col < 32) Xd[row * 32 + col] = (_Float16)acc[j];
        else if (col == 32 && wr_out) out[row * 24 + d] = acc[j];
      }
    }
  }
}

// ---------------- persistent recurrence kernel ----------------
__global__ void __launch_bounds__(NTHR, 1) lstm_main(
    const _Float16* __restrict__ W0e, const _Float16* __restrict__ W1e,
    const _Float16* __restrict__ W0d, const _Float16* __restrict__ W1d,
    const float* __restrict__ bs, _Float16* A1,
    const _Float16* __restrict__ Xe, _Float16* Xd,
    const _Float16* __restrict__ Wfc, const float* __restrict__ bfc,
    float* out, unsigned* gflags)
{
  const int tid = threadIdx.x;
  const int lane = tid & 63, wv = tid >> 6;   // wv = gate index
  const int blk = (int)blockIdx.x;
  const int rowg = blk >> 4, colg = blk & 15;
  const int row0 = rowg * 32, col0 = colg * 32;
  const int row_a = lane & 15;
  const int kq8 = (lane >> 4) * 8;            // per-lane K offset for B frags
  unsigned cnt = 0;

  __shared__ _Float16 Ast[16 * 2 * 64 * 8];   // 32 KB, 16 chunk slots
  __shared__ float Zacc[4 * 32 * 36];         // 18.4 KB gate-acc exchange
  float c0r[4] = {0.f, 0.f, 0.f, 0.f};
  float c1r[4] = {0.f, 0.f, 0.f, 0.f};

  _Float16* bufR = A1;
  _Float16* bufW = A1 + (size_t)512 * 1024;

  // ---- encoder pipeline: phase t computes L0(t) and L1(t-1); t==96's "L0"
  // is the first decoder L0 (x = x_init, W0d), its L1 is enc L1(95).
  for (int t = 0; t < 97; ++t) {
    const bool dec0 = (t == 96);
    const _Float16* W0 = dec0 ? W0d : W0e;
    const float* bs0 = bs + (dec0 ? 4096 : 0);
    const _Float16* xp = dec0 ? Xd : Xe + (size_t)t * 512 * 32;
    const _Float16* w0r0 = W0 + (size_t)(wv * 512 + col0 + row_a) * 544 + kq8;
    const _Float16* w0r1 = W0 + (size_t)(wv * 512 + col0 + 16 + row_a) * 544 + kq8;
    const _Float16* w1r0 = W1e + (size_t)(wv * 512 + col0 + row_a) * 1024 + kq8;
    const _Float16* w1r1 = W1e + (size_t)(wv * 512 + col0 + 16 + row_a) * 1024 + kq8;

    // stage h0(t-1) = bufR cols 512..1023
    stage16(bufR, 512, Ast, row0, tid);
    __syncthreads();
    // L0(t): h-part (W0 k 0..511) + x-part (k 512)
    {
      floatx4 acc[2][2];
      acc_init(acc, bs0, wv, col0, row_a);
      gemm_part<16>(acc, Ast, w0r0, w0r1, 0, lane);
      gemm_x(acc, xp, w0r0, w0r1, 512, row0, lane);
      zwrite(acc, Zacc, wv, lane);
    }
    __syncthreads();
    epi(Zacc, c0r, bufW, row0, 512 + col0, tid);   // h0(t) -> bufW[512+]
    // L1(t-1) part A on the same staging (A cols 512.. -> W1 k 512..)
    floatx4 acc1[2][2];
    if (t >= 1) {
      acc_init(acc1, bs + 2048, wv, col0, row_a);
      gemm_part<16>(acc1, Ast, w1r0, w1r1, 512, lane);
    }
    __syncthreads();                                // all done reading slots
    stage16(bufR, 0, Ast, row0, tid);               // h1(t-2)
    __syncthreads();
    if (t >= 1) {
      gemm_part<16>(acc1, Ast, w1r0, w1r1, 0, lane);
      zwrite(acc1, Zacc, wv, lane);
    }
    __syncthreads();
    if (t >= 1)
      epi(Zacc, c1r, bufW, row0, col0, tid);        // h1(t-1) -> bufW[0+]
    gbar(gflags, cnt, blk);
    _Float16* tmp = bufR; bufR = bufW; bufW = tmp;
  }

  // ---- decoder: bufR = [h1(d-1) | h0(d)]
  for (int d = 0; d < 24; ++d) {
    const _Float16* w1r0 = W1d + (size_t)(wv * 512 + col0 + row_a) * 1024 + kq8;
    const _Float16* w1r1 = W1d + (size_t)(wv * 512 + col0 + 16 + row_a) * 1024 + kq8;
    const _Float16* w0r0 = W0d + (size_t)(wv * 512 + col0 + row_a) * 544 + kq8;
    const _Float16* w0r1 = W0d + (size_t)(wv * 512 + col0 + 16 + row_a) * 544 + kq8;

    // Phase A: h1(d) = L1d([h1(d-1)|h0(d)])
    floatx4 acc1[2][2];
    acc_init(acc1, bs + 6144, wv, col0, row_a);
    stage16(bufR, 512, Ast, row0, tid);   // h0(d)
    __syncthreads();
    gemm_part<16>(acc1, Ast, w1r0, w1r1, 512, lane);
    __syncthreads();
    stage16(bufR, 0, Ast, row0, tid);     // h1(d-1)
    __syncthreads();
    gemm_part<16>(acc1, Ast, w1r0, w1r1, 0, lane);
    zwrite(acc1, Zacc, wv, lane);
    __syncthreads();
    epi(Zacc, c1r, bufW, row0, col0, tid);          // h1(d) -> bufW[0+]
    gbar(gflags, cnt, blk);

    // Phase B: FC heads on h1(d), then L0d(d+1)
    stage16(bufW, 0, Ast, row0, tid);     // h1(d)
    __syncthreads();
    fc_do(Ast, Wfc, bfc, out, Xd, row0, wv, lane, colg == 0, d);
    __syncthreads();                      // Xd visible; slots free
    if (d < 23) {
      stage16(bufR, 512, Ast, row0, tid); // h0(d) again
      __syncthreads();
      floatx4 acc0[2][2];
      acc_init(acc0, bs + 4096, wv, col0, row_a);
      gemm_part<16>(acc0, Ast, w0r0, w0r1, 0, lane);
      gemm_x(acc0, Xd, w0r0, w0r1, 512, row0, lane);
      zwrite(acc0, Zacc, wv, lane);
      __syncthreads();
      epi(Zacc, c0r, bufW, row0, 512 + col0, tid);  // h0(d+1) -> bufW[512+]
      gbar(gflags, cnt, blk);
    }
    _Float16* tmp = bufR; bufR = bufW; bufW = tmp;
  }
}

// ---------------- host ----------------
extern "C" void kernel_launch(void* const* d_in, const int* in_sizes, int n_in,
                              void* d_out, int out_size, void* d_ws, size_t ws_size,
                              hipStream_t stream)
{
  const int base = (in_sizes[2] == 1) ? 3 : 2;
  const float* src   = (const float*)d_in[0];
  const float* eWih0 = (const float*)d_in[base + 0];
  const float* eWhh0 = (const float*)d_in[base + 1];
  const float* ebih0 = (const float*)d_in[base + 2];
  const float* ebhh0 = (const float*)d_in[base + 3];
  const float* eWih1 = (const float*)d_in[base + 4];
  const float* eWhh1 = (const float*)d_in[base + 5];
  const float* ebih1 = (const float*)d_in[base + 6];
  const float* ebhh1 = (const float*)d_in[base + 7];
  const float* dWih0 = (const float*)d_in[base + 8];
  const float* dWhh0 = (const float*)d_in[base + 9];
  const float* dbih0 = (const float*)d_in[base + 10];
  const float* dbhh0 = (const float*)d_in[base + 11];
  const float* dWih1 = (const float*)d_in[base + 12];
  const float* dWhh1 = (const float*)d_in[base + 13];
  const float* dbih1 = (const float*)d_in[base + 14];
  const float* dbhh1 = (const float*)d_in[base + 15];
  const float* fc1w  = (const float*)d_in[base + 16];
  const float* fc1b  = (const float*)d_in[base + 17];
  const float* fc4w  = (const float*)d_in[base + 18];
  const float* fc4b  = (const float*)d_in[base + 19];

  char* p = (char*)d_ws;
  _Float16* W0e = (_Float16*)p; p += 2048 * 544 * 2;
  _Float16* W1e = (_Float16*)p; p += 2048 * 1024 * 2;
  _Float16* W0d = (_Float16*)p; p += 2048 * 544 * 2;
  _Float16* W1d = (_Float16*)p; p += 2048 * 1024 * 2;
  float*    bsv = (float*)p;    p += 8192 * 4;
  _Float16* A1  = (_Float16*)p; p += 2 * 512 * 1024 * 2;
  _Float16* Xe  = (_Float16*)p; p += 96 * 512 * 32 * 2;
  _Float16* Xd  = (_Float16*)p; p += 512 * 32 * 2;
  _Float16* Wfc = (_Float16*)p; p += 48 * 512 * 2;
  float*    bfc = (float*)p;    p += 64 * 4;
  unsigned* gflags = (unsigned*)p; p += 256 * 4;

  hipLaunchKernelGGL(prep_kernel, dim3(1024), dim3(256), 0, stream,
      src, eWih0, eWhh0, ebih0, ebhh0, eWih1, eWhh1, ebih1, ebhh1,
      dWih0, dWhh0, dbih0, dbhh0, dWih1, dWhh1, dbih1, dbhh1,
      fc1w, fc1b, fc4w, fc4b,
      W0e, W1e, W0d, W1d, bsv, A1, Xe, Xd, Wfc, bfc, gflags);

  float* out = (float*)d_out;
  void* kargs[] = { &W0e, &W1e, &W0d, &W1d, &bsv, &A1,
                    &Xe, &Xd, &Wfc, &bfc, &out, &gflags };
  hipLaunchCooperativeKernel(reinterpret_cast<void*>(lstm_main),
                             dim3(NBLK), dim3(NTHR), kargs, 0, stream);
}